// Round 7
// baseline (279.236 us; speedup 1.0000x reference)
//
#include <hip/hip_runtime.h>
#include <hip/hip_bf16.h>
#include <math.h>

// Problem constants (fixed by setup_inputs)
#define BS     8
#define LQ     1000
#define DMODEL 256
#define NH     8
#define NLV    4
#define NPT    4
#define LEN_V  8500          // 80*80+40*40+20*20+10*10
#define NQ     (BS*LQ)       // 8000
#define MV     (BS*LEN_V)    // 68000
#define KS     8             // K=256 / 32 per mfma step

typedef __attribute__((ext_vector_type(8))) short short8;     // 8 bf16 (4 VGPRs)
typedef __attribute__((ext_vector_type(4))) float floatx4;

static __device__ __forceinline__ unsigned short f2bf(float f) {
    __hip_bfloat16 h = __float2bfloat16(f);   // RNE
    return __builtin_bit_cast(unsigned short, h);
}
static __device__ __forceinline__ float asf(unsigned int u) {
    return __builtin_bit_cast(float, u);
}

// ---------------------------------------------------------------------------
// ONE-TILE-PER-BLOCK MFMA GEMM: 64-row x 128-col tiles, A fp32 reg-staged
// (float4 loads -> cvt -> ds_write_b128 at swizzled slots).
// B fragments SELF-GATHERED from the raw fp32 weights (same mapping + RNE cvt
// as the old prep_w kernel -> bit-identical), issued while the A loads fly.
// This removes the prep launch entirely (launch gap ~20-25us > gather cost).
// __launch_bounds__(256,3): VGPR cap ~170 keeps Bf[2][8] register-resident.
// ---------------------------------------------------------------------------
static __device__ __forceinline__ void gemm_tile(
    const float* __restrict__ Aptr,
    const float* __restrict__ W1, const float* __restrict__ W2, int nsplit,
    const float* __restrict__ bias1, const float* __restrict__ bias2,
    void* __restrict__ Cptr, int M, int N, int bn, int bm,
    bool outbf, unsigned short* As /* 16384 shorts = 32KB */)
{
    const int tid = threadIdx.x;
    const int l   = tid & 63;
    const int w   = tid >> 6;          // wave = column quarter (0..3)
    const int lm  = l & 15;
    const int lk  = l >> 4;
    const int x7  = lm & 7;

    // element offset into A for staging slot j (pre-swizzled source)
    auto aoff = [&](int j) -> size_t {
        const int slot = j * 256 + tid;
        const int row  = slot >> 5;
        const int gc   = (slot & 31) ^ (row & 7);     // logical chunk fetched here
        int grow = bm * 64 + row; grow = grow < M ? grow : M - 1;
        return (size_t)grow * 256 + gc * 8;
    };

    // 1) issue A-tile loads first (HBM latency starts ticking)
    float4 ra[8][2];
    #pragma unroll
    for (int j = 0; j < 8; ++j) {
        const float* s = Aptr + aoff(j);
        ra[j][0] = *(const float4*)s;
        ra[j][1] = *(const float4*)(s + 4);
    }

    // 2) B fragments: gather directly from fp32 weights (L2-hot) under the
    //    A-load latency. Mapping == old prep_w: element e of frag (u,s,lane l)
    //    = W[(s*32 + (l>>4)*8 + e) * ld + u*16 + (l&15)], RNE-cvt to bf16.
    short8 Bf[2][KS];
    const int u0 = bn * 8 + w * 2;
    #pragma unroll
    for (int j = 0; j < 2; ++j) {
        const int n = (u0 + j) * 16 + lm;     // fragment col (wave-uniform side)
        const float* wp; int ld;
        if (W2 != nullptr && n >= nsplit) { wp = W2 + (n - nsplit); ld = 128; }
        else                              { wp = W1 + n;            ld = 256; }
        #pragma unroll
        for (int s = 0; s < KS; ++s) {
            const int k0 = s * 32 + lk * 8;
            #pragma unroll
            for (int e = 0; e < 8; ++e)
                Bf[j][s][e] = (short)f2bf(wp[(size_t)(k0 + e) * ld]);
        }
    }

    // 3) drain A -> LDS (swizzled slots)
    #pragma unroll
    for (int j = 0; j < 8; ++j) {
        short8 o;
        o[0] = (short)f2bf(ra[j][0].x); o[1] = (short)f2bf(ra[j][0].y);
        o[2] = (short)f2bf(ra[j][0].z); o[3] = (short)f2bf(ra[j][0].w);
        o[4] = (short)f2bf(ra[j][1].x); o[5] = (short)f2bf(ra[j][1].y);
        o[6] = (short)f2bf(ra[j][1].z); o[7] = (short)f2bf(ra[j][1].w);
        *(short8*)&As[(j * 256 + tid) * 8] = o;
    }
    __syncthreads();

    // 4) K-loop (proven fragment reads / MFMA schedule)
    floatx4 acc[4][2];
    #pragma unroll
    for (int i = 0; i < 4; ++i)
        #pragma unroll
        for (int j = 0; j < 2; ++j)
            #pragma unroll
            for (int r = 0; r < 4; ++r) acc[i][j][r] = 0.f;

    #pragma unroll
    for (int s = 0; s < KS; ++s) {
        short8 afr[4];
        #pragma unroll
        for (int i = 0; i < 4; ++i)
            afr[i] = *(const short8*)(
                &As[(i * 16 + lm) * 256 + (((s * 4 + lk) ^ x7)) * 8]);
        #pragma unroll
        for (int i = 0; i < 4; ++i)
            #pragma unroll
            for (int j = 0; j < 2; ++j)
                acc[i][j] = __builtin_amdgcn_mfma_f32_16x16x32_bf16(
                                afr[i], Bf[j][s], acc[i][j], 0, 0, 0);
    }

    // 5) epilogue
    #pragma unroll
    for (int j = 0; j < 2; ++j) {
        const int col = bn * 128 + w * 32 + j * 16 + lm;
        const float bv = (bias2 != nullptr && col >= nsplit) ? bias2[col - nsplit]
                                                             : bias1[col];
        #pragma unroll
        for (int i = 0; i < 4; ++i) {
            const int rbase = bm * 64 + i * 16 + lk * 4;
            #pragma unroll
            for (int r = 0; r < 4; ++r) {
                const int row = rbase + r;
                if (row < M) {
                    const float v = acc[i][j][r] + bv;
                    if (outbf)
                        ((unsigned short*)Cptr)[(size_t)row * N + col] = f2bf(v);
                    else
                        ((float*)Cptr)[(size_t)row * N + col] = v;
                }
            }
        }
    }
}

// ---- fused GEMMs + w_o fragment prep, ONE launch (2533 blocks):
//      bx <  2126 : v-proj   (1063 M-tiles x 2 col-halves, A=value, B=w_v)
//      bx <  2501 : offattn  ( 125 M-tiles x 3 col-thirds, A=query, B=w_off|w_attn)
//      bx >= 2501 : 32 blocks transform w_o -> wo_f for the sampler launch ----
__global__ __launch_bounds__(256, 3) void gemm_fused(
    const float* __restrict__ value, const float* __restrict__ query,
    const float* __restrict__ w_v, const float* __restrict__ w_off,
    const float* __restrict__ w_attn, const float* __restrict__ w_o,
    const float* __restrict__ b_v, const float* __restrict__ b_off,
    const float* __restrict__ b_attn,
    unsigned short* __restrict__ v_proj, float* __restrict__ offattn,
    unsigned short* __restrict__ wo_f)
{
    __shared__ unsigned short As[16384];
    int bx = blockIdx.x;
    if (bx < 2126) {
        gemm_tile(value, w_v, nullptr, 1 << 30, b_v, nullptr,
                  v_proj, MV, 256, bx & 1, bx >> 1, true, As);
    } else if (bx < 2501) {
        bx -= 2126;
        gemm_tile(query, w_off, w_attn, 256, b_off, b_attn,
                  offattn, NQ, 384, bx % 3, bx / 3, false, As);
    } else {
        // w_o fragment transform (old prep_w mode 2): 8192 chunks / 32 blocks
        const int chunk = (bx - 2501) * 256 + threadIdx.x;
        const int l = chunk & 63, s = (chunk >> 6) & 7, u = chunk >> 9;
        short8 o;
        #pragma unroll
        for (int j = 0; j < 8; ++j) {
            const int k = s * 32 + (l >> 4) * 8 + j;
            const int n = u * 16 + (l & 15);
            o[j] = (short)f2bf(w_o[k * 256 + n]);
        }
        *(short8*)(wo_f + ((size_t)(u * 8 + s) * 64 + l) * 8) = o;
    }
}

// ---------------- softmax + sampling + OUT-PROJECTION (512 thr) ----------------
// 1000 blocks x 512 threads; wave = 1 query for sampling (lp-split as round 0);
// then the 8x256 result tile goes to LDS (rows 8..15 zero) and the 8 waves do
// the out-projection with MFMA (wave w -> cols w*32..w*32+31), writing fp32
// `out` directly. Eliminates the gemm_out launch and the out_pre HBM round-trip.
// NOTE: plain __launch_bounds__(512) -- adding a min-waves arg (512,4) capped
// VGPR at 64 and spilled everything to scratch (282MB WRITE_SIZE, 145us).
__global__ __launch_bounds__(512) void ms_sample_out(
    const unsigned short* __restrict__ v,    // [BS,8500,256] bf16
    const float* __restrict__ offattn,       // [NQ,384]: offs[0:256) | logits[256:384)
    const float* __restrict__ refp,          // [NQ,4,2]
    const unsigned short* __restrict__ wo_f, // w_o fragments
    const float* __restrict__ b_o,
    float* __restrict__ out)                 // [NQ,256] fp32
{
    __shared__ float offx_s[8][16][8];
    __shared__ float offy_s[8][16][8];
    __shared__ float atw_s [8][16][8];
    __shared__ float ref_s [8][8];
    __shared__ float part  [8][32][9];       // [q][h*4+oct][ch], pad 9 vs 8
    __shared__ unsigned short pA[16][256];   // out-proj A tile (rows 8..15 zero)

    const int tid  = threadIdx.x;
    const int bswz = blockIdx.x & 7;                       // batch -> XCD
    const int iq0  = bswz * 1000 + (blockIdx.x >> 3) * 8;  // 8 queries, same batch

    // zero pA rows 8..15 (one ushort4 per thread, exact)
    {
        const int row = 8 + (tid >> 6);
        const int c4  = (tid & 63) * 4;
        ushort4 z; z.x = 0; z.y = 0; z.z = 0; z.w = 0;
        *(ushort4*)&pA[row][c4] = z;
    }

    if (tid < 64) {
        const int q = tid >> 3, h = tid & 7;
        const float* rowp = offattn + (size_t)(iq0 + q) * 384;
        float lg[16];
        float m = -1e30f;
        #pragma unroll
        for (int i = 0; i < 16; ++i) { lg[i] = rowp[256 + h * 16 + i]; m = fmaxf(m, lg[i]); }
        float s = 0.f;
        #pragma unroll
        for (int i = 0; i < 16; ++i) { lg[i] = __expf(lg[i] - m); s += lg[i]; }
        const float inv = 1.f / s;
        #pragma unroll
        for (int i = 0; i < 16; ++i) atw_s[q][i][h] = lg[i] * inv;
        #pragma unroll
        for (int i = 0; i < 16; ++i) {
            offx_s[q][i][h] = rowp[(h * 16 + i) * 2 + 0];
            offy_s[q][i][h] = rowp[(h * 16 + i) * 2 + 1];
        }
        if (h == 0) {
            #pragma unroll
            for (int i = 0; i < 8; ++i) ref_s[q][i] = refp[(size_t)(iq0 + q) * 8 + i];
        }
    }
    __syncthreads();

    const int q8   = tid >> 6;
    const int half = (tid >> 5) & 1;
    const int sub  = tid & 31;
    const int h    = sub >> 2;
    const int oct  = sub & 3;

    float acc[8] = {0.f, 0.f, 0.f, 0.f, 0.f, 0.f, 0.f, 0.f};
    const unsigned short* vb = v + (size_t)bswz * LEN_V * 256 + h * 32 + oct * 8;
    const int Hs[4] = {80, 40, 20, 10};
    const int st[4] = {0, 6400, 8000, 8400};

    #pragma unroll
    for (int li = 0; li < 2; ++li) {
        const int lvl = half * 2 + li;
        const int W = Hs[lvl];
        const float bx = ref_s[q8][lvl * 2 + 0] * (float)W - 0.5f;
        const float by = ref_s[q8][lvl * 2 + 1] * (float)W - 0.5f;
        const unsigned short* vl = vb + (size_t)st[lvl] * 256;
        #pragma unroll
        for (int p = 0; p < NPT; ++p) {
            const int lp = lvl * 4 + p;
            const float x  = bx + offx_s[q8][lp][h];
            const float y  = by + offy_s[q8][lp][h];
            const float at = atw_s[q8][lp][h];
            const float x0f = floorf(x), y0f = floorf(y);
            const float fx = x - x0f, fy = y - y0f;
            const int x0 = (int)x0f, y0 = (int)y0f;
            const int x1 = x0 + 1,   y1 = y0 + 1;
            const int cx0 = min(max(x0, 0), W - 1);
            const int cx1 = min(max(x1, 0), W - 1);
            const int cy0 = min(max(y0, 0), W - 1);
            const int cy1 = min(max(y1, 0), W - 1);
            const float vx0 = (x0 >= 0 && x0 < W) ? 1.f : 0.f;
            const float vx1 = (x1 >= 0 && x1 < W) ? 1.f : 0.f;
            const float vy0 = (y0 >= 0 && y0 < W) ? 1.f : 0.f;
            const float vy1 = (y1 >= 0 && y1 < W) ? 1.f : 0.f;
            const float w00 = at * (1.f - fx) * (1.f - fy) * vx0 * vy0;
            const float w01 = at * fx * (1.f - fy) * vx1 * vy0;
            const float w10 = at * (1.f - fx) * fy * vx0 * vy1;
            const float w11 = at * fx * fy * vx1 * vy1;
            const unsigned short* r0 = vl + (size_t)(cy0 * W) * 256;
            const unsigned short* r1 = vl + (size_t)(cy1 * W) * 256;
            const uint4 d00 = *(const uint4*)(r0 + (size_t)cx0 * 256);
            const uint4 d01 = *(const uint4*)(r0 + (size_t)cx1 * 256);
            const uint4 d10 = *(const uint4*)(r1 + (size_t)cx0 * 256);
            const uint4 d11 = *(const uint4*)(r1 + (size_t)cx1 * 256);
            acc[0] += w00 * asf(d00.x << 16) + w01 * asf(d01.x << 16)
                    + w10 * asf(d10.x << 16) + w11 * asf(d11.x << 16);
            acc[1] += w00 * asf(d00.x & 0xffff0000u) + w01 * asf(d01.x & 0xffff0000u)
                    + w10 * asf(d10.x & 0xffff0000u) + w11 * asf(d11.x & 0xffff0000u);
            acc[2] += w00 * asf(d00.y << 16) + w01 * asf(d01.y << 16)
                    + w10 * asf(d10.y << 16) + w11 * asf(d11.y << 16);
            acc[3] += w00 * asf(d00.y & 0xffff0000u) + w01 * asf(d01.y & 0xffff0000u)
                    + w10 * asf(d10.y & 0xffff0000u) + w11 * asf(d11.y & 0xffff0000u);
            acc[4] += w00 * asf(d00.z << 16) + w01 * asf(d01.z << 16)
                    + w10 * asf(d10.z << 16) + w11 * asf(d11.z << 16);
            acc[5] += w00 * asf(d00.z & 0xffff0000u) + w01 * asf(d01.z & 0xffff0000u)
                    + w10 * asf(d10.z & 0xffff0000u) + w11 * asf(d11.z & 0xffff0000u);
            acc[6] += w00 * asf(d00.w << 16) + w01 * asf(d01.w << 16)
                    + w10 * asf(d10.w << 16) + w11 * asf(d11.w << 16);
            acc[7] += w00 * asf(d00.w & 0xffff0000u) + w01 * asf(d01.w & 0xffff0000u)
                    + w10 * asf(d10.w & 0xffff0000u) + w11 * asf(d11.w & 0xffff0000u);
        }
    }

    if (half == 1) {
        #pragma unroll
        for (int j = 0; j < 8; ++j) part[q8][sub][j] = acc[j];
    }
    __syncthreads();
    if (half == 0) {
        short8 o;
        #pragma unroll
        for (int j = 0; j < 8; ++j) o[j] = (short)f2bf(acc[j] + part[q8][sub][j]);
        *(short8*)&pA[q8][sub * 8] = o;      // rows 0..7 = the 8 queries
    }
    __syncthreads();

    // ---- out-projection: wave w -> cols w*32..w*32+31 (u0 = w*2, NF=2) ----
    const int l  = tid & 63;
    const int w8 = tid >> 6;                 // 8 waves
    const int lm = l & 15;
    const int lk = l >> 4;

    floatx4 oacc[2];
    #pragma unroll
    for (int j = 0; j < 2; ++j)
        #pragma unroll
        for (int r = 0; r < 4; ++r) oacc[j][r] = 0.f;

    #pragma unroll
    for (int s = 0; s < KS; ++s) {
        const short8 a = *(const short8*)&pA[lm][(s * 4 + lk) * 8];
        #pragma unroll
        for (int j = 0; j < 2; ++j) {
            const short8 b = *(const short8*)(
                wo_f + ((size_t)((w8 * 2 + j) * KS + s) * 64 + l) * 8);
            oacc[j] = __builtin_amdgcn_mfma_f32_16x16x32_bf16(a, b, oacc[j], 0, 0, 0);
        }
    }

    if (lk < 2) {                            // rows 0..7 valid (the 8 queries)
        #pragma unroll
        for (int j = 0; j < 2; ++j) {
            const int col = w8 * 32 + j * 16 + lm;
            const float bo = b_o[col];
            #pragma unroll
            for (int r = 0; r < 4; ++r) {
                const int q = lk * 4 + r;
                out[(size_t)(iq0 + q) * 256 + col] = oacc[j][r] + bo;
            }
        }
    }
}

// ------------------------------- launcher -------------------------------
extern "C" void kernel_launch(void* const* d_in, const int* in_sizes, int n_in,
                              void* d_out, int out_size, void* d_ws, size_t ws_size,
                              hipStream_t stream)
{
    const float* query  = (const float*)d_in[0];
    const float* refp   = (const float*)d_in[1];
    const float* value  = (const float*)d_in[2];
    const float* w_off  = (const float*)d_in[3];
    const float* b_off  = (const float*)d_in[4];
    const float* w_attn = (const float*)d_in[5];
    const float* b_attn = (const float*)d_in[6];
    const float* w_v    = (const float*)d_in[7];
    const float* b_v    = (const float*)d_in[8];
    const float* w_o    = (const float*)d_in[9];
    const float* b_o    = (const float*)d_in[10];
    (void)d_in[11]; (void)d_in[12];  // shapes/starts fixed by problem, hardcoded

    float* out = (float*)d_out;

    // workspace layout (bytes):
    //   v_proj   34,816,000   (68000 x 256 bf16)
    //   offattn  12,288,000   (8000 x 384 f32)
    //   wo_f        131,072
    char* ws = (char*)d_ws;
    unsigned short* v_proj  = (unsigned short*)ws;
    float*          offattn = (float*)(ws + 34816000);
    unsigned short* wo_f    = (unsigned short*)(ws + 47104000);

    // 1) v-proj + offattn GEMMs (B self-gathered from fp32 weights) + w_o prep
    hipLaunchKernelGGL(gemm_fused, dim3(2533), dim3(256), 0, stream,
                       value, query, w_v, w_off, w_attn, w_o,
                       b_v, b_off, b_attn, v_proj, offattn, wo_f);
    // 2) sampling + softmax + out-projection -> out (fp32)
    hipLaunchKernelGGL(ms_sample_out, dim3(1000), dim3(512), 0, stream,
                       v_proj, offattn, refp, wo_f, b_o, out);
}

// Round 8
// 270.115 us; speedup vs baseline: 1.0338x; 1.0338x over previous
//
#include <hip/hip_runtime.h>
#include <hip/hip_bf16.h>
#include <math.h>

// Problem constants (fixed by setup_inputs)
#define BS     8
#define LQ     1000
#define DMODEL 256
#define NH     8
#define NLV    4
#define NPT    4
#define LEN_V  8500          // 80*80+40*40+20*20+10*10
#define NQ     (BS*LQ)       // 8000
#define MV     (BS*LEN_V)    // 68000
#define KS     8             // K=256 / 32 per mfma step

typedef __attribute__((ext_vector_type(8))) short short8;     // 8 bf16 (4 VGPRs)
typedef __attribute__((ext_vector_type(4))) float floatx4;

static __device__ __forceinline__ unsigned short f2bf(float f) {
    __hip_bfloat16 h = __float2bfloat16(f);   // RNE
    return __builtin_bit_cast(unsigned short, h);
}
static __device__ __forceinline__ float asf(unsigned int u) {
    return __builtin_bit_cast(float, u);
}

// ---------------------------------------------------------------------------
// ONE-TILE-PER-BLOCK MFMA GEMM: 64-row x (NF*64)-col tiles, A fp32 reg-staged
// (float4 loads -> cvt -> ds_write_b128 at swizzled slots). B fragments from
// the prep_w fragment buffer (L2-hot; demotion/remat is harmless -- r3).
// NF=4: full-width 256-col tile (each A read serves ALL cols -> fewer HBM
// re-reads; the GEMM is pinned at ~2.9 TB/s effective BW, so bytes==time).
// NF=2: 128-col tile (offattn thirds).
// ---------------------------------------------------------------------------
template <int NF>
static __device__ __forceinline__ void gemm_tile(
    const float* __restrict__ Aptr, const unsigned short* __restrict__ Bfrag,
    const float* __restrict__ bias1, const float* __restrict__ bias2, int nsplit,
    void* __restrict__ Cptr, int M, int N, int bn, int bm,
    bool outbf, unsigned short* As /* 16384 shorts = 32KB */)
{
    const int tid = threadIdx.x;
    const int l   = tid & 63;
    const int w   = tid >> 6;          // wave index (0..3)
    const int lm  = l & 15;
    const int lk  = l >> 4;
    const int x7  = lm & 7;

    // element offset into A for staging slot j (pre-swizzled source)
    auto aoff = [&](int j) -> size_t {
        const int slot = j * 256 + tid;
        const int row  = slot >> 5;
        const int gc   = (slot & 31) ^ (row & 7);     // logical chunk fetched here
        int grow = bm * 64 + row; grow = grow < M ? grow : M - 1;
        return (size_t)grow * 256 + gc * 8;
    };

    // 1) issue A-tile loads first (HBM latency starts ticking)
    float4 ra[8][2];
    #pragma unroll
    for (int j = 0; j < 8; ++j) {
        const float* s = Aptr + aoff(j);
        ra[j][0] = *(const float4*)s;
        ra[j][1] = *(const float4*)(s + 4);
    }

    // 2) B fragments fly under the A loads (fragment buffer is L2-hot)
    short8 Bf[NF][KS];
    const int u0 = bn * 8 + w * NF;
    #pragma unroll
    for (int j = 0; j < NF; ++j)
        #pragma unroll
        for (int s = 0; s < KS; ++s)
            Bf[j][s] = *(const short8*)(Bfrag + ((size_t)((u0 + j) * KS + s) * 64 + l) * 8);

    // 3) drain A -> LDS (swizzled slots)
    #pragma unroll
    for (int j = 0; j < 8; ++j) {
        short8 o;
        o[0] = (short)f2bf(ra[j][0].x); o[1] = (short)f2bf(ra[j][0].y);
        o[2] = (short)f2bf(ra[j][0].z); o[3] = (short)f2bf(ra[j][0].w);
        o[4] = (short)f2bf(ra[j][1].x); o[5] = (short)f2bf(ra[j][1].y);
        o[6] = (short)f2bf(ra[j][1].z); o[7] = (short)f2bf(ra[j][1].w);
        *(short8*)&As[(j * 256 + tid) * 8] = o;
    }
    __syncthreads();

    // 4) K-loop (proven fragment reads / MFMA schedule)
    floatx4 acc[4][NF];
    #pragma unroll
    for (int i = 0; i < 4; ++i)
        #pragma unroll
        for (int j = 0; j < NF; ++j)
            #pragma unroll
            for (int r = 0; r < 4; ++r) acc[i][j][r] = 0.f;

    #pragma unroll
    for (int s = 0; s < KS; ++s) {
        short8 afr[4];
        #pragma unroll
        for (int i = 0; i < 4; ++i)
            afr[i] = *(const short8*)(
                &As[(i * 16 + lm) * 256 + (((s * 4 + lk) ^ x7)) * 8]);
        #pragma unroll
        for (int i = 0; i < 4; ++i)
            #pragma unroll
            for (int j = 0; j < NF; ++j)
                acc[i][j] = __builtin_amdgcn_mfma_f32_16x16x32_bf16(
                                afr[i], Bf[j][s], acc[i][j], 0, 0, 0);
    }

    // 5) epilogue
    #pragma unroll
    for (int j = 0; j < NF; ++j) {
        const int col = bn * 128 + w * (16 * NF) + j * 16 + lm;
        const float bv = (bias2 != nullptr && col >= nsplit) ? bias2[col - nsplit]
                                                             : bias1[col];
        #pragma unroll
        for (int i = 0; i < 4; ++i) {
            const int rbase = bm * 64 + i * 16 + lk * 4;
            #pragma unroll
            for (int r = 0; r < 4; ++r) {
                const int row = rbase + r;
                if (row < M) {
                    const float v = acc[i][j][r] + bv;
                    if (outbf)
                        ((unsigned short*)Cptr)[(size_t)row * N + col] = f2bf(v);
                    else
                        ((float*)Cptr)[(size_t)row * N + col] = v;
                }
            }
        }
    }
}

// ---- fused independent GEMMs, one tile per block:
//      v-proj  (1063 blocks: full-width 64x256 tiles, A=value)
//      offattn ( 375 blocks: 125 M-tiles x 3 col-thirds, A=query) ----
__global__ __launch_bounds__(256, 3) void gemm_fused(
    const float* __restrict__ value, const float* __restrict__ query,
    const unsigned short* __restrict__ wv_f, const unsigned short* __restrict__ woa_f,
    const float* __restrict__ b_v, const float* __restrict__ b_off,
    const float* __restrict__ b_attn,
    unsigned short* __restrict__ v_proj, float* __restrict__ offattn)
{
    __shared__ unsigned short As[16384];
    int bx = blockIdx.x;
    if (bx < 1063) {
        gemm_tile<4>(value, wv_f, b_v, nullptr, 1 << 30,
                     v_proj, MV, 256, 0, bx, true, As);
    } else {
        bx -= 1063;
        gemm_tile<2>(query, woa_f, b_off, b_attn, 256,
                     offattn, NQ, 384, bx % 3, bx / 3, false, As);
    }
}

// ---- prep: weight transform to MFMA fragment layout (112 blocks, tiny) ----
__global__ __launch_bounds__(256) void prep_w(
    const float* __restrict__ w_v, const float* __restrict__ w_off,
    const float* __restrict__ w_attn, const float* __restrict__ w_o,
    unsigned short* __restrict__ wv_f, unsigned short* __restrict__ woa_f,
    unsigned short* __restrict__ wo_f)
{
    const int gid = blockIdx.x * 256 + threadIdx.x;     // 28672 total, exact
    int chunk, mode;
    if (gid < 8192)               { chunk = gid;         mode = 0; }
    else if (gid < 8192 + 12288)  { chunk = gid - 8192;  mode = 1; }
    else                          { chunk = gid - 20480; mode = 2; }
    const int l = chunk & 63, s = (chunk >> 6) & 7, u = chunk >> 9;
    short8 o;
    #pragma unroll
    for (int j = 0; j < 8; ++j) {
        const int k = s * 32 + (l >> 4) * 8 + j;
        const int n = u * 16 + (l & 15);
        float v;
        if (mode == 0)      v = w_v[k * 256 + n];
        else if (mode == 1) v = (n < 256) ? w_off[k * 256 + n] : w_attn[k * 128 + (n - 256)];
        else                v = w_o[k * 256 + n];
        o[j] = (short)f2bf(v);
    }
    unsigned short* dp = (mode == 0 ? wv_f : mode == 1 ? woa_f : wo_f)
                         + ((size_t)(u * 8 + s) * 64 + l) * 8;
    *(short8*)dp = o;
}

// ---------------- softmax + sampling + OUT-PROJECTION (512 thr) ----------------
// 1000 blocks x 512 threads; wave = 1 query for sampling (lp-split); then the
// 8x256 result tile goes to LDS (rows 8..15 zero) and the 8 waves do the
// out-projection with MFMA, writing fp32 `out` directly.
// __launch_bounds__(512, 3): 3 blocks/CU (cap ~85 VGPR; live set ~60 so no
// spill expected -- verify via WRITE_SIZE ~8MB). (512,4) capped at 64 and
// spilled catastrophically (r5: 282MB WRITE, 145us); plain 512 gave 128/2blk.
__global__ __launch_bounds__(512, 3) void ms_sample_out(
    const unsigned short* __restrict__ v,    // [BS,8500,256] bf16
    const float* __restrict__ offattn,       // [NQ,384]: offs[0:256) | logits[256:384)
    const float* __restrict__ refp,          // [NQ,4,2]
    const unsigned short* __restrict__ wo_f, // w_o fragments
    const float* __restrict__ b_o,
    float* __restrict__ out)                 // [NQ,256] fp32
{
    __shared__ float offx_s[8][16][8];
    __shared__ float offy_s[8][16][8];
    __shared__ float atw_s [8][16][8];
    __shared__ float ref_s [8][8];
    __shared__ float part  [8][32][9];       // [q][h*4+oct][ch], pad 9 vs 8
    __shared__ unsigned short pA[16][256];   // out-proj A tile (rows 8..15 zero)

    const int tid  = threadIdx.x;
    const int bswz = blockIdx.x & 7;                       // batch -> XCD
    const int iq0  = bswz * 1000 + (blockIdx.x >> 3) * 8;  // 8 queries, same batch

    // zero pA rows 8..15 (one ushort4 per thread, exact)
    {
        const int row = 8 + (tid >> 6);
        const int c4  = (tid & 63) * 4;
        ushort4 z; z.x = 0; z.y = 0; z.z = 0; z.w = 0;
        *(ushort4*)&pA[row][c4] = z;
    }

    if (tid < 64) {
        const int q = tid >> 3, h = tid & 7;
        const float* rowp = offattn + (size_t)(iq0 + q) * 384;
        float lg[16];
        float m = -1e30f;
        #pragma unroll
        for (int i = 0; i < 16; ++i) { lg[i] = rowp[256 + h * 16 + i]; m = fmaxf(m, lg[i]); }
        float s = 0.f;
        #pragma unroll
        for (int i = 0; i < 16; ++i) { lg[i] = __expf(lg[i] - m); s += lg[i]; }
        const float inv = 1.f / s;
        #pragma unroll
        for (int i = 0; i < 16; ++i) atw_s[q][i][h] = lg[i] * inv;
        #pragma unroll
        for (int i = 0; i < 16; ++i) {
            offx_s[q][i][h] = rowp[(h * 16 + i) * 2 + 0];
            offy_s[q][i][h] = rowp[(h * 16 + i) * 2 + 1];
        }
        if (h == 0) {
            #pragma unroll
            for (int i = 0; i < 8; ++i) ref_s[q][i] = refp[(size_t)(iq0 + q) * 8 + i];
        }
    }
    __syncthreads();

    const int q8   = tid >> 6;
    const int half = (tid >> 5) & 1;
    const int sub  = tid & 31;
    const int h    = sub >> 2;
    const int oct  = sub & 3;

    float acc[8] = {0.f, 0.f, 0.f, 0.f, 0.f, 0.f, 0.f, 0.f};
    const unsigned short* vb = v + (size_t)bswz * LEN_V * 256 + h * 32 + oct * 8;
    const int Hs[4] = {80, 40, 20, 10};
    const int st[4] = {0, 6400, 8000, 8400};

    #pragma unroll
    for (int li = 0; li < 2; ++li) {
        const int lvl = half * 2 + li;
        const int W = Hs[lvl];
        const float bx = ref_s[q8][lvl * 2 + 0] * (float)W - 0.5f;
        const float by = ref_s[q8][lvl * 2 + 1] * (float)W - 0.5f;
        const unsigned short* vl = vb + (size_t)st[lvl] * 256;
        #pragma unroll
        for (int p = 0; p < NPT; ++p) {
            const int lp = lvl * 4 + p;
            const float x  = bx + offx_s[q8][lp][h];
            const float y  = by + offy_s[q8][lp][h];
            const float at = atw_s[q8][lp][h];
            const float x0f = floorf(x), y0f = floorf(y);
            const float fx = x - x0f, fy = y - y0f;
            const int x0 = (int)x0f, y0 = (int)y0f;
            const int x1 = x0 + 1,   y1 = y0 + 1;
            const int cx0 = min(max(x0, 0), W - 1);
            const int cx1 = min(max(x1, 0), W - 1);
            const int cy0 = min(max(y0, 0), W - 1);
            const int cy1 = min(max(y1, 0), W - 1);
            const float vx0 = (x0 >= 0 && x0 < W) ? 1.f : 0.f;
            const float vx1 = (x1 >= 0 && x1 < W) ? 1.f : 0.f;
            const float vy0 = (y0 >= 0 && y0 < W) ? 1.f : 0.f;
            const float vy1 = (y1 >= 0 && y1 < W) ? 1.f : 0.f;
            const float w00 = at * (1.f - fx) * (1.f - fy) * vx0 * vy0;
            const float w01 = at * fx * (1.f - fy) * vx1 * vy0;
            const float w10 = at * (1.f - fx) * fy * vx0 * vy1;
            const float w11 = at * fx * fy * vx1 * vy1;
            const unsigned short* r0 = vl + (size_t)(cy0 * W) * 256;
            const unsigned short* r1 = vl + (size_t)(cy1 * W) * 256;
            const uint4 d00 = *(const uint4*)(r0 + (size_t)cx0 * 256);
            const uint4 d01 = *(const uint4*)(r0 + (size_t)cx1 * 256);
            const uint4 d10 = *(const uint4*)(r1 + (size_t)cx0 * 256);
            const uint4 d11 = *(const uint4*)(r1 + (size_t)cx1 * 256);
            acc[0] += w00 * asf(d00.x << 16) + w01 * asf(d01.x << 16)
                    + w10 * asf(d10.x << 16) + w11 * asf(d11.x << 16);
            acc[1] += w00 * asf(d00.x & 0xffff0000u) + w01 * asf(d01.x & 0xffff0000u)
                    + w10 * asf(d10.x & 0xffff0000u) + w11 * asf(d11.x & 0xffff0000u);
            acc[2] += w00 * asf(d00.y << 16) + w01 * asf(d01.y << 16)
                    + w10 * asf(d10.y << 16) + w11 * asf(d11.y << 16);
            acc[3] += w00 * asf(d00.y & 0xffff0000u) + w01 * asf(d01.y & 0xffff0000u)
                    + w10 * asf(d10.y & 0xffff0000u) + w11 * asf(d11.y & 0xffff0000u);
            acc[4] += w00 * asf(d00.z << 16) + w01 * asf(d01.z << 16)
                    + w10 * asf(d10.z << 16) + w11 * asf(d11.z << 16);
            acc[5] += w00 * asf(d00.z & 0xffff0000u) + w01 * asf(d01.z & 0xffff0000u)
                    + w10 * asf(d10.z & 0xffff0000u) + w11 * asf(d11.z & 0xffff0000u);
            acc[6] += w00 * asf(d00.w << 16) + w01 * asf(d01.w << 16)
                    + w10 * asf(d10.w << 16) + w11 * asf(d11.w << 16);
            acc[7] += w00 * asf(d00.w & 0xffff0000u) + w01 * asf(d01.w & 0xffff0000u)
                    + w10 * asf(d10.w & 0xffff0000u) + w11 * asf(d11.w & 0xffff0000u);
        }
    }

    if (half == 1) {
        #pragma unroll
        for (int j = 0; j < 8; ++j) part[q8][sub][j] = acc[j];
    }
    __syncthreads();
    if (half == 0) {
        short8 o;
        #pragma unroll
        for (int j = 0; j < 8; ++j) o[j] = (short)f2bf(acc[j] + part[q8][sub][j]);
        *(short8*)&pA[q8][sub * 8] = o;      // rows 0..7 = the 8 queries
    }
    __syncthreads();

    // ---- out-projection: wave w -> cols w*32..w*32+31 (u0 = w*2, NF=2) ----
    const int l  = tid & 63;
    const int w8 = tid >> 6;                 // 8 waves
    const int lm = l & 15;
    const int lk = l >> 4;

    floatx4 oacc[2];
    #pragma unroll
    for (int j = 0; j < 2; ++j)
        #pragma unroll
        for (int r = 0; r < 4; ++r) oacc[j][r] = 0.f;

    #pragma unroll
    for (int s = 0; s < KS; ++s) {
        const short8 a = *(const short8*)&pA[lm][(s * 4 + lk) * 8];
        #pragma unroll
        for (int j = 0; j < 2; ++j) {
            const short8 b = *(const short8*)(
                wo_f + ((size_t)((w8 * 2 + j) * KS + s) * 64 + l) * 8);
            oacc[j] = __builtin_amdgcn_mfma_f32_16x16x32_bf16(a, b, oacc[j], 0, 0, 0);
        }
    }

    if (lk < 2) {                            // rows 0..7 valid (the 8 queries)
        #pragma unroll
        for (int j = 0; j < 2; ++j) {
            const int col = w8 * 32 + j * 16 + lm;
            const float bo = b_o[col];
            #pragma unroll
            for (int r = 0; r < 4; ++r) {
                const int q = lk * 4 + r;
                out[(size_t)(iq0 + q) * 256 + col] = oacc[j][r] + bo;
            }
        }
    }
}

// ------------------------------- launcher -------------------------------
extern "C" void kernel_launch(void* const* d_in, const int* in_sizes, int n_in,
                              void* d_out, int out_size, void* d_ws, size_t ws_size,
                              hipStream_t stream)
{
    const float* query  = (const float*)d_in[0];
    const float* refp   = (const float*)d_in[1];
    const float* value  = (const float*)d_in[2];
    const float* w_off  = (const float*)d_in[3];
    const float* b_off  = (const float*)d_in[4];
    const float* w_attn = (const float*)d_in[5];
    const float* b_attn = (const float*)d_in[6];
    const float* w_v    = (const float*)d_in[7];
    const float* b_v    = (const float*)d_in[8];
    const float* w_o    = (const float*)d_in[9];
    const float* b_o    = (const float*)d_in[10];
    (void)d_in[11]; (void)d_in[12];  // shapes/starts fixed by problem, hardcoded

    float* out = (float*)d_out;

    // workspace layout (bytes):
    //   v_proj   34,816,000   (68000 x 256 bf16)
    //   offattn  12,288,000   (8000 x 384 f32)
    //   weights     458,752
    char* ws = (char*)d_ws;
    unsigned short* v_proj  = (unsigned short*)ws;
    float*          offattn = (float*)(ws + 34816000);
    unsigned short* wv_f    = (unsigned short*)(ws + 47104000);
    unsigned short* woa_f   = (unsigned short*)(ws + 47235072);
    unsigned short* wo_f    = (unsigned short*)(ws + 47431680);

    dim3 blk(256);

    // 1) weight fragment transform (112 blocks, ~2us)
    hipLaunchKernelGGL(prep_w, dim3(112), blk, 0, stream,
                       w_v, w_off, w_attn, w_o, wv_f, woa_f, wo_f);
    // 2) v-proj (full-width tiles) + offattn in one launch
    hipLaunchKernelGGL(gemm_fused, dim3(1438), blk, 0, stream,
                       value, query, wv_f, woa_f, b_v, b_off, b_attn, v_proj, offattn);
    // 3) sampling + softmax + out-projection -> out (fp32)
    hipLaunchKernelGGL(ms_sample_out, dim3(1000), dim3(512), 0, stream,
                       v_proj, offattn, refp, wo_f, b_o, out);
}

// Round 10
// 184.192 us; speedup vs baseline: 1.5160x; 1.4665x over previous
//
#include <hip/hip_runtime.h>
#include <hip/hip_bf16.h>
#include <math.h>

// Problem constants (fixed by setup_inputs)
#define BS     8
#define LQ     1000
#define DMODEL 256
#define NH     8
#define NLV    4
#define NPT    4
#define LEN_V  8500          // 80*80+40*40+20*20+10*10
#define NQ     (BS*LQ)       // 8000
#define MV     (BS*LEN_V)    // 68000
#define KS     8             // K=256 / 32 per mfma step

typedef __attribute__((ext_vector_type(8))) short short8;     // 8 bf16 (4 VGPRs)
typedef __attribute__((ext_vector_type(4))) float floatx4;

static __device__ __forceinline__ unsigned short f2bf(float f) {
    __hip_bfloat16 h = __float2bfloat16(f);   // RNE
    return __builtin_bit_cast(unsigned short, h);
}
static __device__ __forceinline__ float asf(unsigned int u) {
    return __builtin_bit_cast(float, u);
}

// ---------------------------------------------------------------------------
// ONE-TILE-PER-BLOCK MFMA GEMM (r2/r6 proven): 64-row x 128-col tiles,
// A fp32 reg-staged (float4 loads -> cvt -> ds_write_b128 at swizzled slots).
// __launch_bounds__(256,3): VGPR cap ~170 keeps Bf[2][8] register-resident.
// ---------------------------------------------------------------------------
static __device__ __forceinline__ void gemm_tile(
    const float* __restrict__ Aptr, const unsigned short* __restrict__ Bfrag,
    const float* __restrict__ bias1, const float* __restrict__ bias2, int nsplit,
    void* __restrict__ Cptr, int M, int N, int bn, int bm,
    bool outbf, unsigned short* As /* 16384 shorts = 32KB */)
{
    const int tid = threadIdx.x;
    const int l   = tid & 63;
    const int w   = tid >> 6;          // wave = column quarter (0..3)
    const int lm  = l & 15;
    const int lk  = l >> 4;
    const int x7  = lm & 7;

    // element offset into A for staging slot j (pre-swizzled source)
    auto aoff = [&](int j) -> size_t {
        const int slot = j * 256 + tid;
        const int row  = slot >> 5;
        const int gc   = (slot & 31) ^ (row & 7);     // logical chunk fetched here
        int grow = bm * 64 + row; grow = grow < M ? grow : M - 1;
        return (size_t)grow * 256 + gc * 8;
    };

    // 1) issue A-tile loads first (HBM latency starts ticking)
    float4 ra[8][2];
    #pragma unroll
    for (int j = 0; j < 8; ++j) {
        const float* s = Aptr + aoff(j);
        ra[j][0] = *(const float4*)s;
        ra[j][1] = *(const float4*)(s + 4);
    }

    // 2) B fragments fly under the A loads (fragment buffer is L2-hot)
    short8 Bf[2][KS];
    const int u0 = bn * 8 + w * 2;
    #pragma unroll
    for (int j = 0; j < 2; ++j)
        #pragma unroll
        for (int s = 0; s < KS; ++s)
            Bf[j][s] = *(const short8*)(Bfrag + ((size_t)((u0 + j) * KS + s) * 64 + l) * 8);

    // 3) drain A -> LDS (swizzled slots)
    #pragma unroll
    for (int j = 0; j < 8; ++j) {
        short8 o;
        o[0] = (short)f2bf(ra[j][0].x); o[1] = (short)f2bf(ra[j][0].y);
        o[2] = (short)f2bf(ra[j][0].z); o[3] = (short)f2bf(ra[j][0].w);
        o[4] = (short)f2bf(ra[j][1].x); o[5] = (short)f2bf(ra[j][1].y);
        o[6] = (short)f2bf(ra[j][1].z); o[7] = (short)f2bf(ra[j][1].w);
        *(short8*)&As[(j * 256 + tid) * 8] = o;
    }
    __syncthreads();

    // 4) K-loop (proven fragment reads / MFMA schedule)
    floatx4 acc[4][2];
    #pragma unroll
    for (int i = 0; i < 4; ++i)
        #pragma unroll
        for (int j = 0; j < 2; ++j)
            #pragma unroll
            for (int r = 0; r < 4; ++r) acc[i][j][r] = 0.f;

    #pragma unroll
    for (int s = 0; s < KS; ++s) {
        short8 afr[4];
        #pragma unroll
        for (int i = 0; i < 4; ++i)
            afr[i] = *(const short8*)(
                &As[(i * 16 + lm) * 256 + (((s * 4 + lk) ^ x7)) * 8]);
        #pragma unroll
        for (int i = 0; i < 4; ++i)
            #pragma unroll
            for (int j = 0; j < 2; ++j)
                acc[i][j] = __builtin_amdgcn_mfma_f32_16x16x32_bf16(
                                afr[i], Bf[j][s], acc[i][j], 0, 0, 0);
    }

    // 5) epilogue
    #pragma unroll
    for (int j = 0; j < 2; ++j) {
        const int col = bn * 128 + w * 32 + j * 16 + lm;
        const float bv = (bias2 != nullptr && col >= nsplit) ? bias2[col - nsplit]
                                                             : bias1[col];
        #pragma unroll
        for (int i = 0; i < 4; ++i) {
            const int rbase = bm * 64 + i * 16 + lk * 4;
            #pragma unroll
            for (int r = 0; r < 4; ++r) {
                const int row = rbase + r;
                if (row < M) {
                    const float v = acc[i][j][r] + bv;
                    if (outbf)
                        ((unsigned short*)Cptr)[(size_t)row * N + col] = f2bf(v);
                    else
                        ((float*)Cptr)[(size_t)row * N + col] = v;
                }
            }
        }
    }
}

// ---- fused independent GEMMs, one tile per block:
//      v-proj: 2128 block slots, XCD-PAIRED swizzle -- both column-halves of
//        an A-tile land on the SAME XCD back-to-back (xcd = bx&7, tile =
//        xcd*133 + ((bx>>3)>>1), half = (bx>>3)&1; bijective over 1064 slots,
//        slot 1063 idle) so the 64KB A re-read hits that XCD's L2 instead of
//        L3. Pure index permutation -- no memory/sync/numeric change.
//      offattn: 375 blocks (125 M-tiles x 3 col-thirds, A=query) ----
__global__ __launch_bounds__(256, 3) void gemm_fused(
    const float* __restrict__ value, const float* __restrict__ query,
    const unsigned short* __restrict__ wv_f, const unsigned short* __restrict__ woa_f,
    const float* __restrict__ b_v, const float* __restrict__ b_off,
    const float* __restrict__ b_attn,
    unsigned short* __restrict__ v_proj, float* __restrict__ offattn)
{
    __shared__ unsigned short As[16384];
    int bx = blockIdx.x;
    if (bx < 2128) {
        const int xcd  = bx & 7;
        const int k    = bx >> 3;              // 0..265
        const int tile = xcd * 133 + (k >> 1); // 0..1063
        const int half = k & 1;
        if (tile < 1063)                       // block-uniform: slot 1063 idle
            gemm_tile(value, wv_f, b_v, nullptr, 1 << 30,
                      v_proj, MV, 256, half, tile, true, As);
    } else {
        bx -= 2128;
        gemm_tile(query, woa_f, b_off, b_attn, 256,
                  offattn, NQ, 384, bx % 3, bx / 3, false, As);
    }
}

// ---- prep: weight transform to MFMA fragment layout (112 blocks, tiny) ----
__global__ __launch_bounds__(256) void prep_w(
    const float* __restrict__ w_v, const float* __restrict__ w_off,
    const float* __restrict__ w_attn, const float* __restrict__ w_o,
    unsigned short* __restrict__ wv_f, unsigned short* __restrict__ woa_f,
    unsigned short* __restrict__ wo_f)
{
    const int gid = blockIdx.x * 256 + threadIdx.x;     // 28672 total, exact
    int chunk, mode;
    if (gid < 8192)               { chunk = gid;         mode = 0; }
    else if (gid < 8192 + 12288)  { chunk = gid - 8192;  mode = 1; }
    else                          { chunk = gid - 20480; mode = 2; }
    const int l = chunk & 63, s = (chunk >> 6) & 7, u = chunk >> 9;
    short8 o;
    #pragma unroll
    for (int j = 0; j < 8; ++j) {
        const int k = s * 32 + (l >> 4) * 8 + j;
        const int n = u * 16 + (l & 15);
        float v;
        if (mode == 0)      v = w_v[k * 256 + n];
        else if (mode == 1) v = (n < 256) ? w_off[k * 256 + n] : w_attn[k * 128 + (n - 256)];
        else                v = w_o[k * 256 + n];
        o[j] = (short)f2bf(v);
    }
    unsigned short* dp = (mode == 0 ? wv_f : mode == 1 ? woa_f : wo_f)
                         + ((size_t)(u * 8 + s) * 64 + l) * 8;
    *(short8*)dp = o;
}

// ---------------- softmax + sampling + OUT-PROJECTION (512 thr) ----------------
// r6-proven sampler, byte-identical. 1000 blocks x 512 threads; wave = 1 query
// for sampling (lp-split); 8x256 result tile -> LDS pA (rows 8..15 zero) ->
// 8 waves MFMA out-projection -> fp32 `out` directly.
// NOTE: plain __launch_bounds__(512) -- any min-waves cap (512,3)/(512,4)
// forces VGPR <= 85/64 and spills catastrophically (r5: 282MB, r8: 206MB).
__global__ __launch_bounds__(512) void ms_sample_out(
    const unsigned short* __restrict__ v,    // [BS,8500,256] bf16
    const float* __restrict__ offattn,       // [NQ,384]: offs[0:256) | logits[256:384)
    const float* __restrict__ refp,          // [NQ,4,2]
    const unsigned short* __restrict__ wo_f, // w_o fragments
    const float* __restrict__ b_o,
    float* __restrict__ out)                 // [NQ,256] fp32
{
    __shared__ float offx_s[8][16][8];
    __shared__ float offy_s[8][16][8];
    __shared__ float atw_s [8][16][8];
    __shared__ float ref_s [8][8];
    __shared__ float part  [8][32][9];       // [q][h*4+oct][ch], pad 9 vs 8
    __shared__ unsigned short pA[16][256];   // out-proj A tile (rows 8..15 zero)

    const int tid  = threadIdx.x;
    const int bswz = blockIdx.x & 7;                       // batch -> XCD
    const int iq0  = bswz * 1000 + (blockIdx.x >> 3) * 8;  // 8 queries, same batch

    // zero pA rows 8..15 (one ushort4 per thread, exact)
    {
        const int row = 8 + (tid >> 6);
        const int c4  = (tid & 63) * 4;
        ushort4 z; z.x = 0; z.y = 0; z.z = 0; z.w = 0;
        *(ushort4*)&pA[row][c4] = z;
    }

    if (tid < 64) {
        const int q = tid >> 3, h = tid & 7;
        const float* rowp = offattn + (size_t)(iq0 + q) * 384;
        float lg[16];
        float m = -1e30f;
        #pragma unroll
        for (int i = 0; i < 16; ++i) { lg[i] = rowp[256 + h * 16 + i]; m = fmaxf(m, lg[i]); }
        float s = 0.f;
        #pragma unroll
        for (int i = 0; i < 16; ++i) { lg[i] = __expf(lg[i] - m); s += lg[i]; }
        const float inv = 1.f / s;
        #pragma unroll
        for (int i = 0; i < 16; ++i) atw_s[q][i][h] = lg[i] * inv;
        #pragma unroll
        for (int i = 0; i < 16; ++i) {
            offx_s[q][i][h] = rowp[(h * 16 + i) * 2 + 0];
            offy_s[q][i][h] = rowp[(h * 16 + i) * 2 + 1];
        }
        if (h == 0) {
            #pragma unroll
            for (int i = 0; i < 8; ++i) ref_s[q][i] = refp[(size_t)(iq0 + q) * 8 + i];
        }
    }
    __syncthreads();

    const int q8   = tid >> 6;
    const int half = (tid >> 5) & 1;
    const int sub  = tid & 31;
    const int h    = sub >> 2;
    const int oct  = sub & 3;

    float acc[8] = {0.f, 0.f, 0.f, 0.f, 0.f, 0.f, 0.f, 0.f};
    const unsigned short* vb = v + (size_t)bswz * LEN_V * 256 + h * 32 + oct * 8;
    const int Hs[4] = {80, 40, 20, 10};
    const int st[4] = {0, 6400, 8000, 8400};

    #pragma unroll
    for (int li = 0; li < 2; ++li) {
        const int lvl = half * 2 + li;
        const int W = Hs[lvl];
        const float bx = ref_s[q8][lvl * 2 + 0] * (float)W - 0.5f;
        const float by = ref_s[q8][lvl * 2 + 1] * (float)W - 0.5f;
        const unsigned short* vl = vb + (size_t)st[lvl] * 256;
        #pragma unroll
        for (int p = 0; p < NPT; ++p) {
            const int lp = lvl * 4 + p;
            const float x  = bx + offx_s[q8][lp][h];
            const float y  = by + offy_s[q8][lp][h];
            const float at = atw_s[q8][lp][h];
            const float x0f = floorf(x), y0f = floorf(y);
            const float fx = x - x0f, fy = y - y0f;
            const int x0 = (int)x0f, y0 = (int)y0f;
            const int x1 = x0 + 1,   y1 = y0 + 1;
            const int cx0 = min(max(x0, 0), W - 1);
            const int cx1 = min(max(x1, 0), W - 1);
            const int cy0 = min(max(y0, 0), W - 1);
            const int cy1 = min(max(y1, 0), W - 1);
            const float vx0 = (x0 >= 0 && x0 < W) ? 1.f : 0.f;
            const float vx1 = (x1 >= 0 && x1 < W) ? 1.f : 0.f;
            const float vy0 = (y0 >= 0 && y0 < W) ? 1.f : 0.f;
            const float vy1 = (y1 >= 0 && y1 < W) ? 1.f : 0.f;
            const float w00 = at * (1.f - fx) * (1.f - fy) * vx0 * vy0;
            const float w01 = at * fx * (1.f - fy) * vx1 * vy0;
            const float w10 = at * (1.f - fx) * fy * vx0 * vy1;
            const float w11 = at * fx * fy * vx1 * vy1;
            const unsigned short* r0 = vl + (size_t)(cy0 * W) * 256;
            const unsigned short* r1 = vl + (size_t)(cy1 * W) * 256;
            const uint4 d00 = *(const uint4*)(r0 + (size_t)cx0 * 256);
            const uint4 d01 = *(const uint4*)(r0 + (size_t)cx1 * 256);
            const uint4 d10 = *(const uint4*)(r1 + (size_t)cx0 * 256);
            const uint4 d11 = *(const uint4*)(r1 + (size_t)cx1 * 256);
            acc[0] += w00 * asf(d00.x << 16) + w01 * asf(d01.x << 16)
                    + w10 * asf(d10.x << 16) + w11 * asf(d11.x << 16);
            acc[1] += w00 * asf(d00.x & 0xffff0000u) + w01 * asf(d01.x & 0xffff0000u)
                    + w10 * asf(d10.x & 0xffff0000u) + w11 * asf(d11.x & 0xffff0000u);
            acc[2] += w00 * asf(d00.y << 16) + w01 * asf(d01.y << 16)
                    + w10 * asf(d10.y << 16) + w11 * asf(d11.y << 16);
            acc[3] += w00 * asf(d00.y & 0xffff0000u) + w01 * asf(d01.y & 0xffff0000u)
                    + w10 * asf(d10.y & 0xffff0000u) + w11 * asf(d11.y & 0xffff0000u);
            acc[4] += w00 * asf(d00.z << 16) + w01 * asf(d01.z << 16)
                    + w10 * asf(d10.z << 16) + w11 * asf(d11.z << 16);
            acc[5] += w00 * asf(d00.z & 0xffff0000u) + w01 * asf(d01.z & 0xffff0000u)
                    + w10 * asf(d10.z & 0xffff0000u) + w11 * asf(d11.z & 0xffff0000u);
            acc[6] += w00 * asf(d00.w << 16) + w01 * asf(d01.w << 16)
                    + w10 * asf(d10.w << 16) + w11 * asf(d11.w << 16);
            acc[7] += w00 * asf(d00.w & 0xffff0000u) + w01 * asf(d01.w & 0xffff0000u)
                    + w10 * asf(d10.w & 0xffff0000u) + w11 * asf(d11.w & 0xffff0000u);
        }
    }

    if (half == 1) {
        #pragma unroll
        for (int j = 0; j < 8; ++j) part[q8][sub][j] = acc[j];
    }
    __syncthreads();
    if (half == 0) {
        short8 o;
        #pragma unroll
        for (int j = 0; j < 8; ++j) o[j] = (short)f2bf(acc[j] + part[q8][sub][j]);
        *(short8*)&pA[q8][sub * 8] = o;      // rows 0..7 = the 8 queries
    }
    __syncthreads();

    // ---- out-projection: wave w -> cols w*32..w*32+31 (u0 = w*2, NF=2) ----
    const int l  = tid & 63;
    const int w8 = tid >> 6;                 // 8 waves
    const int lm = l & 15;
    const int lk = l >> 4;

    floatx4 oacc[2];
    #pragma unroll
    for (int j = 0; j < 2; ++j)
        #pragma unroll
        for (int r = 0; r < 4; ++r) oacc[j][r] = 0.f;

    #pragma unroll
    for (int s = 0; s < KS; ++s) {
        const short8 a = *(const short8*)&pA[lm][(s * 4 + lk) * 8];
        #pragma unroll
        for (int j = 0; j < 2; ++j) {
            const short8 b = *(const short8*)(
                wo_f + ((size_t)((w8 * 2 + j) * KS + s) * 64 + l) * 8);
            oacc[j] = __builtin_amdgcn_mfma_f32_16x16x32_bf16(a, b, oacc[j], 0, 0, 0);
        }
    }

    if (lk < 2) {                            // rows 0..7 valid (the 8 queries)
        #pragma unroll
        for (int j = 0; j < 2; ++j) {
            const int col = w8 * 32 + j * 16 + lm;
            const float bo = b_o[col];
            #pragma unroll
            for (int r = 0; r < 4; ++r) {
                const int q = lk * 4 + r;
                out[(size_t)(iq0 + q) * 256 + col] = oacc[j][r] + bo;
            }
        }
    }
}

// ------------------------------- launcher -------------------------------
extern "C" void kernel_launch(void* const* d_in, const int* in_sizes, int n_in,
                              void* d_out, int out_size, void* d_ws, size_t ws_size,
                              hipStream_t stream)
{
    const float* query  = (const float*)d_in[0];
    const float* refp   = (const float*)d_in[1];
    const float* value  = (const float*)d_in[2];
    const float* w_off  = (const float*)d_in[3];
    const float* b_off  = (const float*)d_in[4];
    const float* w_attn = (const float*)d_in[5];
    const float* b_attn = (const float*)d_in[6];
    const float* w_v    = (const float*)d_in[7];
    const float* b_v    = (const float*)d_in[8];
    const float* w_o    = (const float*)d_in[9];
    const float* b_o    = (const float*)d_in[10];
    (void)d_in[11]; (void)d_in[12];  // shapes/starts fixed by problem, hardcoded

    float* out = (float*)d_out;

    // workspace layout (bytes):
    //   v_proj   34,816,000   (68000 x 256 bf16)
    //   offattn  12,288,000   (8000 x 384 f32)
    //   weights     458,752
    char* ws = (char*)d_ws;
    unsigned short* v_proj  = (unsigned short*)ws;
    float*          offattn = (float*)(ws + 34816000);
    unsigned short* wv_f    = (unsigned short*)(ws + 47104000);
    unsigned short* woa_f   = (unsigned short*)(ws + 47235072);
    unsigned short* wo_f    = (unsigned short*)(ws + 47431680);

    dim3 blk(256);

    // 1) weight fragment transform (112 blocks, ~2us)
    hipLaunchKernelGGL(prep_w, dim3(112), blk, 0, stream,
                       w_v, w_off, w_attn, w_o, wv_f, woa_f, wo_f);
    // 2) v-proj (XCD-paired swizzle) + offattn in one launch
    hipLaunchKernelGGL(gemm_fused, dim3(2503), blk, 0, stream,
                       value, query, wv_f, woa_f, b_v, b_off, b_attn, v_proj, offattn);
    // 3) sampling + softmax + out-projection -> out (fp32)
    hipLaunchKernelGGL(ms_sample_out, dim3(1000), dim3(512), 0, stream,
                       v_proj, offattn, refp, wo_f, b_o, out);
}

// Round 11
// 181.680 us; speedup vs baseline: 1.5370x; 1.0138x over previous
//
#include <hip/hip_runtime.h>
#include <hip/hip_bf16.h>
#include <math.h>

// Problem constants (fixed by setup_inputs)
#define BS     8
#define LQ     1000
#define DMODEL 256
#define NH     8
#define NLV    4
#define NPT    4
#define LEN_V  8500          // 80*80+40*40+20*20+10*10
#define NQ     (BS*LQ)       // 8000
#define MV     (BS*LEN_V)    // 68000
#define KS     8             // K=256 / 32 per mfma step

typedef __attribute__((ext_vector_type(8))) short short8;     // 8 bf16 (4 VGPRs)
typedef __attribute__((ext_vector_type(4))) float floatx4;

static __device__ __forceinline__ unsigned short f2bf(float f) {
    __hip_bfloat16 h = __float2bfloat16(f);   // RNE
    return __builtin_bit_cast(unsigned short, h);
}
static __device__ __forceinline__ float asf(unsigned int u) {
    return __builtin_bit_cast(float, u);
}

// ---------------------------------------------------------------------------
// ONE-TILE-PER-BLOCK MFMA GEMM (r2/r6/r10 proven): 64-row x 128-col tiles,
// A fp32 reg-staged (float4 loads -> cvt -> ds_write_b128 at swizzled slots).
// __launch_bounds__(256,3). Latency-bound at ~47us (r10: FETCH 81->47MB via
// XCD pairing, dur unchanged -> NOT BW-bound; 8 structural variants all 47-50).
// ---------------------------------------------------------------------------
static __device__ __forceinline__ void gemm_tile(
    const float* __restrict__ Aptr, const unsigned short* __restrict__ Bfrag,
    const float* __restrict__ bias1, const float* __restrict__ bias2, int nsplit,
    void* __restrict__ Cptr, int M, int N, int bn, int bm,
    bool outbf, unsigned short* As /* 16384 shorts = 32KB */)
{
    const int tid = threadIdx.x;
    const int l   = tid & 63;
    const int w   = tid >> 6;          // wave = column quarter (0..3)
    const int lm  = l & 15;
    const int lk  = l >> 4;
    const int x7  = lm & 7;

    // element offset into A for staging slot j (pre-swizzled source)
    auto aoff = [&](int j) -> size_t {
        const int slot = j * 256 + tid;
        const int row  = slot >> 5;
        const int gc   = (slot & 31) ^ (row & 7);     // logical chunk fetched here
        int grow = bm * 64 + row; grow = grow < M ? grow : M - 1;
        return (size_t)grow * 256 + gc * 8;
    };

    // 1) issue A-tile loads first (HBM latency starts ticking)
    float4 ra[8][2];
    #pragma unroll
    for (int j = 0; j < 8; ++j) {
        const float* s = Aptr + aoff(j);
        ra[j][0] = *(const float4*)s;
        ra[j][1] = *(const float4*)(s + 4);
    }

    // 2) B fragments fly under the A loads (fragment buffer is L2-hot)
    short8 Bf[2][KS];
    const int u0 = bn * 8 + w * 2;
    #pragma unroll
    for (int j = 0; j < 2; ++j)
        #pragma unroll
        for (int s = 0; s < KS; ++s)
            Bf[j][s] = *(const short8*)(Bfrag + ((size_t)((u0 + j) * KS + s) * 64 + l) * 8);

    // 3) drain A -> LDS (swizzled slots)
    #pragma unroll
    for (int j = 0; j < 8; ++j) {
        short8 o;
        o[0] = (short)f2bf(ra[j][0].x); o[1] = (short)f2bf(ra[j][0].y);
        o[2] = (short)f2bf(ra[j][0].z); o[3] = (short)f2bf(ra[j][0].w);
        o[4] = (short)f2bf(ra[j][1].x); o[5] = (short)f2bf(ra[j][1].y);
        o[6] = (short)f2bf(ra[j][1].z); o[7] = (short)f2bf(ra[j][1].w);
        *(short8*)&As[(j * 256 + tid) * 8] = o;
    }
    __syncthreads();

    // 4) K-loop (proven fragment reads / MFMA schedule)
    floatx4 acc[4][2];
    #pragma unroll
    for (int i = 0; i < 4; ++i)
        #pragma unroll
        for (int j = 0; j < 2; ++j)
            #pragma unroll
            for (int r = 0; r < 4; ++r) acc[i][j][r] = 0.f;

    #pragma unroll
    for (int s = 0; s < KS; ++s) {
        short8 afr[4];
        #pragma unroll
        for (int i = 0; i < 4; ++i)
            afr[i] = *(const short8*)(
                &As[(i * 16 + lm) * 256 + (((s * 4 + lk) ^ x7)) * 8]);
        #pragma unroll
        for (int i = 0; i < 4; ++i)
            #pragma unroll
            for (int j = 0; j < 2; ++j)
                acc[i][j] = __builtin_amdgcn_mfma_f32_16x16x32_bf16(
                                afr[i], Bf[j][s], acc[i][j], 0, 0, 0);
    }

    // 5) epilogue
    #pragma unroll
    for (int j = 0; j < 2; ++j) {
        const int col = bn * 128 + w * 32 + j * 16 + lm;
        const float bv = (bias2 != nullptr && col >= nsplit) ? bias2[col - nsplit]
                                                             : bias1[col];
        #pragma unroll
        for (int i = 0; i < 4; ++i) {
            const int rbase = bm * 64 + i * 16 + lk * 4;
            #pragma unroll
            for (int r = 0; r < 4; ++r) {
                const int row = rbase + r;
                if (row < M) {
                    const float v = acc[i][j][r] + bv;
                    if (outbf)
                        ((unsigned short*)Cptr)[(size_t)row * N + col] = f2bf(v);
                    else
                        ((float*)Cptr)[(size_t)row * N + col] = v;
                }
            }
        }
    }
}

// ---- fused independent GEMMs, one tile per block (r10 proven, incl. grid
//      count 2503 = 2128 + 375 -- r9's failure was a 2501 grid with this map):
//      v-proj: 2128 slots, XCD-PAIRED swizzle (both column-halves of a tile
//        on the same XCD back-to-back; FETCH 81->47MB). tile 1063 idle.
//      offattn: 375 blocks (125 M-tiles x 3 col-thirds, A=query) ----
__global__ __launch_bounds__(256, 3) void gemm_fused(
    const float* __restrict__ value, const float* __restrict__ query,
    const unsigned short* __restrict__ wv_f, const unsigned short* __restrict__ woa_f,
    const float* __restrict__ b_v, const float* __restrict__ b_off,
    const float* __restrict__ b_attn,
    unsigned short* __restrict__ v_proj, float* __restrict__ offattn)
{
    __shared__ unsigned short As[16384];
    int bx = blockIdx.x;
    if (bx < 2128) {
        const int xcd  = bx & 7;
        const int k    = bx >> 3;              // 0..265
        const int tile = xcd * 133 + (k >> 1); // 0..1063
        const int half = k & 1;
        if (tile < 1063)                       // block-uniform: slot 1063 idle
            gemm_tile(value, wv_f, b_v, nullptr, 1 << 30,
                      v_proj, MV, 256, half, tile, true, As);
    } else {
        bx -= 2128;
        gemm_tile(query, woa_f, b_off, b_attn, 256,
                  offattn, NQ, 384, bx % 3, bx / 3, false, As);
    }
}

// ---- prep: weight transform to MFMA fragment layout (112 blocks, tiny) ----
__global__ __launch_bounds__(256) void prep_w(
    const float* __restrict__ w_v, const float* __restrict__ w_off,
    const float* __restrict__ w_attn, const float* __restrict__ w_o,
    unsigned short* __restrict__ wv_f, unsigned short* __restrict__ woa_f,
    unsigned short* __restrict__ wo_f)
{
    const int gid = blockIdx.x * 256 + threadIdx.x;     // 28672 total, exact
    int chunk, mode;
    if (gid < 8192)               { chunk = gid;         mode = 0; }
    else if (gid < 8192 + 12288)  { chunk = gid - 8192;  mode = 1; }
    else                          { chunk = gid - 20480; mode = 2; }
    const int l = chunk & 63, s = (chunk >> 6) & 7, u = chunk >> 9;
    short8 o;
    #pragma unroll
    for (int j = 0; j < 8; ++j) {
        const int k = s * 32 + (l >> 4) * 8 + j;
        const int n = u * 16 + (l & 15);
        float v;
        if (mode == 0)      v = w_v[k * 256 + n];
        else if (mode == 1) v = (n < 256) ? w_off[k * 256 + n] : w_attn[k * 128 + (n - 256)];
        else                v = w_o[k * 256 + n];
        o[j] = (short)f2bf(v);
    }
    unsigned short* dp = (mode == 0 ? wv_f : mode == 1 ? woa_f : wo_f)
                         + ((size_t)(u * 8 + s) * 64 + l) * 8;
    *(short8*)dp = o;
}

// ---------------- softmax + sampling + OUT-PROJECTION (512 thr) ----------------
// 4-CHANNEL decomposition: wave = 1 query, lane = one 4-channel slot (8 heads
// x 8 slots); each lane walks ALL 16 points with uint2 (8B) gathers. Same
// bytes/coalescing as the 8-ch version, but acc[4] + uint2 in flight -> live
// set shrinks structurally; no part[] exchange, one fewer barrier. NO
// launch-bounds cap (r5/r8: forced caps spill; if compiler lands <=85 VGPR
// naturally we get 3 blocks/CU free). Then 8x256 tile -> pA -> MFMA out-proj.
// (r9 ran this sampler but with a 2501 grid vs the gemm's 2503 slots -- two
// offattn tiles never computed -> uninit reads -> the determinism failure.)
__global__ __launch_bounds__(512) void ms_sample_out(
    const unsigned short* __restrict__ v,    // [BS,8500,256] bf16
    const float* __restrict__ offattn,       // [NQ,384]: offs[0:256) | logits[256:384)
    const float* __restrict__ refp,          // [NQ,4,2]
    const unsigned short* __restrict__ wo_f, // w_o fragments
    const float* __restrict__ b_o,
    float* __restrict__ out)                 // [NQ,256] fp32
{
    __shared__ float offx_s[8][16][8];
    __shared__ float offy_s[8][16][8];
    __shared__ float atw_s [8][16][8];
    __shared__ float ref_s [8][8];
    __shared__ unsigned short pA[16][256];   // out-proj A tile (rows 8..15 zero)

    const int tid  = threadIdx.x;
    const int bswz = blockIdx.x & 7;                       // batch -> XCD
    const int iq0  = bswz * 1000 + (blockIdx.x >> 3) * 8;  // 8 queries, same batch

    // zero pA rows 8..15 (one ushort4 per thread, exact)
    {
        const int row = 8 + (tid >> 6);
        const int c4  = (tid & 63) * 4;
        ushort4 z; z.x = 0; z.y = 0; z.z = 0; z.w = 0;
        *(ushort4*)&pA[row][c4] = z;
    }

    if (tid < 64) {
        const int q = tid >> 3, h = tid & 7;
        const float* rowp = offattn + (size_t)(iq0 + q) * 384;
        float lg[16];
        float m = -1e30f;
        #pragma unroll
        for (int i = 0; i < 16; ++i) { lg[i] = rowp[256 + h * 16 + i]; m = fmaxf(m, lg[i]); }
        float s = 0.f;
        #pragma unroll
        for (int i = 0; i < 16; ++i) { lg[i] = __expf(lg[i] - m); s += lg[i]; }
        const float inv = 1.f / s;
        #pragma unroll
        for (int i = 0; i < 16; ++i) atw_s[q][i][h] = lg[i] * inv;
        #pragma unroll
        for (int i = 0; i < 16; ++i) {
            offx_s[q][i][h] = rowp[(h * 16 + i) * 2 + 0];
            offy_s[q][i][h] = rowp[(h * 16 + i) * 2 + 1];
        }
        if (h == 0) {
            #pragma unroll
            for (int i = 0; i < 8; ++i) ref_s[q][i] = refp[(size_t)(iq0 + q) * 8 + i];
        }
    }
    __syncthreads();

    const int q8 = tid >> 6;                 // wave = query
    const int cs = tid & 63;                 // channel slot (h*8 + s4)
    const int h  = cs >> 3;
    const int s4 = cs & 7;                   // 4-channel group within head

    float acc[4] = {0.f, 0.f, 0.f, 0.f};
    const unsigned short* vb = v + (size_t)bswz * LEN_V * 256 + h * 32 + s4 * 4;
    const int Hs[4] = {80, 40, 20, 10};
    const int st[4] = {0, 6400, 8000, 8400};

    #pragma unroll
    for (int lvl = 0; lvl < NLV; ++lvl) {
        const int W = Hs[lvl];
        const float bx = ref_s[q8][lvl * 2 + 0] * (float)W - 0.5f;
        const float by = ref_s[q8][lvl * 2 + 1] * (float)W - 0.5f;
        const unsigned short* vl = vb + (size_t)st[lvl] * 256;
        #pragma unroll
        for (int p = 0; p < NPT; ++p) {
            const int lp = lvl * 4 + p;
            const float x  = bx + offx_s[q8][lp][h];
            const float y  = by + offy_s[q8][lp][h];
            const float at = atw_s[q8][lp][h];
            const float x0f = floorf(x), y0f = floorf(y);
            const float fx = x - x0f, fy = y - y0f;
            const int x0 = (int)x0f, y0 = (int)y0f;
            const int x1 = x0 + 1,   y1 = y0 + 1;
            const int cx0 = min(max(x0, 0), W - 1);
            const int cx1 = min(max(x1, 0), W - 1);
            const int cy0 = min(max(y0, 0), W - 1);
            const int cy1 = min(max(y1, 0), W - 1);
            const float vx0 = (x0 >= 0 && x0 < W) ? 1.f : 0.f;
            const float vx1 = (x1 >= 0 && x1 < W) ? 1.f : 0.f;
            const float vy0 = (y0 >= 0 && y0 < W) ? 1.f : 0.f;
            const float vy1 = (y1 >= 0 && y1 < W) ? 1.f : 0.f;
            const float w00 = at * (1.f - fx) * (1.f - fy) * vx0 * vy0;
            const float w01 = at * fx * (1.f - fy) * vx1 * vy0;
            const float w10 = at * (1.f - fx) * fy * vx0 * vy1;
            const float w11 = at * fx * fy * vx1 * vy1;
            const unsigned short* r0 = vl + (size_t)(cy0 * W) * 256;
            const unsigned short* r1 = vl + (size_t)(cy1 * W) * 256;
            const uint2 d00 = *(const uint2*)(r0 + (size_t)cx0 * 256);
            const uint2 d01 = *(const uint2*)(r0 + (size_t)cx1 * 256);
            const uint2 d10 = *(const uint2*)(r1 + (size_t)cx0 * 256);
            const uint2 d11 = *(const uint2*)(r1 + (size_t)cx1 * 256);
            acc[0] += w00 * asf(d00.x << 16) + w01 * asf(d01.x << 16)
                    + w10 * asf(d10.x << 16) + w11 * asf(d11.x << 16);
            acc[1] += w00 * asf(d00.x & 0xffff0000u) + w01 * asf(d01.x & 0xffff0000u)
                    + w10 * asf(d10.x & 0xffff0000u) + w11 * asf(d11.x & 0xffff0000u);
            acc[2] += w00 * asf(d00.y << 16) + w01 * asf(d01.y << 16)
                    + w10 * asf(d10.y << 16) + w11 * asf(d11.y << 16);
            acc[3] += w00 * asf(d00.y & 0xffff0000u) + w01 * asf(d01.y & 0xffff0000u)
                    + w10 * asf(d10.y & 0xffff0000u) + w11 * asf(d11.y & 0xffff0000u);
        }
    }

    {
        ushort4 o;
        o.x = f2bf(acc[0]); o.y = f2bf(acc[1]);
        o.z = f2bf(acc[2]); o.w = f2bf(acc[3]);
        *(ushort4*)&pA[q8][cs * 4] = o;      // rows 0..7 = the 8 queries
    }
    __syncthreads();

    // ---- out-projection: wave w -> cols w*32..w*32+31 (u0 = w*2, NF=2) ----
    const int l  = tid & 63;
    const int w8 = tid >> 6;                 // 8 waves
    const int lm = l & 15;
    const int lk = l >> 4;

    floatx4 oacc[2];
    #pragma unroll
    for (int j = 0; j < 2; ++j)
        #pragma unroll
        for (int r = 0; r < 4; ++r) oacc[j][r] = 0.f;

    #pragma unroll
    for (int s = 0; s < KS; ++s) {
        const short8 a = *(const short8*)&pA[lm][(s * 4 + lk) * 8];
        #pragma unroll
        for (int j = 0; j < 2; ++j) {
            const short8 b = *(const short8*)(
                wo_f + ((size_t)((w8 * 2 + j) * KS + s) * 64 + l) * 8);
            oacc[j] = __builtin_amdgcn_mfma_f32_16x16x32_bf16(a, b, oacc[j], 0, 0, 0);
        }
    }

    if (lk < 2) {                            // rows 0..7 valid (the 8 queries)
        #pragma unroll
        for (int j = 0; j < 2; ++j) {
            const int col = w8 * 32 + j * 16 + lm;
            const float bo = b_o[col];
            #pragma unroll
            for (int r = 0; r < 4; ++r) {
                const int q = lk * 4 + r;
                out[(size_t)(iq0 + q) * 256 + col] = oacc[j][r] + bo;
            }
        }
    }
}

// ------------------------------- launcher -------------------------------
extern "C" void kernel_launch(void* const* d_in, const int* in_sizes, int n_in,
                              void* d_out, int out_size, void* d_ws, size_t ws_size,
                              hipStream_t stream)
{
    const float* query  = (const float*)d_in[0];
    const float* refp   = (const float*)d_in[1];
    const float* value  = (const float*)d_in[2];
    const float* w_off  = (const float*)d_in[3];
    const float* b_off  = (const float*)d_in[4];
    const float* w_attn = (const float*)d_in[5];
    const float* b_attn = (const float*)d_in[6];
    const float* w_v    = (const float*)d_in[7];
    const float* b_v    = (const float*)d_in[8];
    const float* w_o    = (const float*)d_in[9];
    const float* b_o    = (const float*)d_in[10];
    (void)d_in[11]; (void)d_in[12];  // shapes/starts fixed by problem, hardcoded

    float* out = (float*)d_out;

    // workspace layout (bytes):
    //   v_proj   34,816,000   (68000 x 256 bf16)
    //   offattn  12,288,000   (8000 x 384 f32)
    //   weights     458,752
    char* ws = (char*)d_ws;
    unsigned short* v_proj  = (unsigned short*)ws;
    float*          offattn = (float*)(ws + 34816000);
    unsigned short* wv_f    = (unsigned short*)(ws + 47104000);
    unsigned short* woa_f   = (unsigned short*)(ws + 47235072);
    unsigned short* wo_f    = (unsigned short*)(ws + 47431680);

    dim3 blk(256);

    // 1) weight fragment transform (112 blocks, ~2us)
    hipLaunchKernelGGL(prep_w, dim3(112), blk, 0, stream,
                       w_v, w_off, w_attn, w_o, wv_f, woa_f, wo_f);
    // 2) v-proj (XCD-paired swizzle) + offattn in one launch (2503 = 2128+375)
    hipLaunchKernelGGL(gemm_fused, dim3(2503), blk, 0, stream,
                       value, query, wv_f, woa_f, b_v, b_off, b_attn, v_proj, offattn);
    // 3) sampling (4-ch lanes) + softmax + out-projection -> out (fp32)
    hipLaunchKernelGGL(ms_sample_out, dim3(1000), dim3(512), 0, stream,
                       v_proj, offattn, refp, wo_f, b_o, out);
}